// Round 1
// baseline (407.302 us; speedup 1.0000x reference)
//
#include <hip/hip_runtime.h>

// ReconstructionLoss: loss = mean(|masks - onehot(argmax_c(src_stft[:,:,:F,:]))|)
// Shapes: masks [16,512,1024,4] f32, src_stft [16,512,2048,4] f32, out = scalar f32.
// Memory-bound: 268 MB read -> ~43 us ideal at 6.3 TB/s.

#define C_PER_GROUP 4
#define F_DIM 1024          // power of 2: use shift/mask, no int div
#define F_SHIFT 10
#define F_MASK 1023

__global__ __launch_bounds__(256) void recon_loss_kernel(
    const float4* __restrict__ masks,   // G groups of 4 floats
    const float4* __restrict__ src,     // per (b,t): F_DIM gt groups then F_DIM phase groups
    float* __restrict__ out,
    unsigned int G, float inv_n)
{
    unsigned int tid    = blockIdx.x * blockDim.x + threadIdx.x;
    unsigned int stride = gridDim.x * blockDim.x;

    float acc = 0.0f;
    for (unsigned int g = tid; g < G; g += stride) {
        unsigned int bt = g >> F_SHIFT;         // which (b,t) slab
        unsigned int f  = g & F_MASK;           // position inside magnitude half
        float4 gt = src[(bt << (F_SHIFT + 1)) | f];  // stride 2F groups per (b,t)
        float4 m  = masks[g];

        // first-max argmax over 4 (strict > keeps the first max, like jnp/torch)
        int   idx  = 0;
        float best = gt.x;
        if (gt.y > best) { best = gt.y; idx = 1; }
        if (gt.z > best) { best = gt.z; idx = 2; }
        if (gt.w > best) { best = gt.w; idx = 3; }

        acc += fabsf(m.x - (idx == 0 ? 1.0f : 0.0f));
        acc += fabsf(m.y - (idx == 1 ? 1.0f : 0.0f));
        acc += fabsf(m.z - (idx == 2 ? 1.0f : 0.0f));
        acc += fabsf(m.w - (idx == 3 ? 1.0f : 0.0f));
    }

    // wave-64 butterfly reduce
    #pragma unroll
    for (int off = 32; off > 0; off >>= 1)
        acc += __shfl_down(acc, off, 64);

    __shared__ float wave_sums[4];   // 256 threads / 64 = 4 waves
    int lane = threadIdx.x & 63;
    int wave = threadIdx.x >> 6;
    if (lane == 0) wave_sums[wave] = acc;
    __syncthreads();

    if (threadIdx.x == 0) {
        float blk = wave_sums[0] + wave_sums[1] + wave_sums[2] + wave_sums[3];
        atomicAdd(out, blk * inv_n);   // pre-scaled: accumulates the mean directly
    }
}

extern "C" void kernel_launch(void* const* d_in, const int* in_sizes, int n_in,
                              void* d_out, int out_size, void* d_ws, size_t ws_size,
                              hipStream_t stream) {
    const float4* masks = (const float4*)d_in[0];
    const float4* src   = (const float4*)d_in[1];
    float* out = (float*)d_out;

    const unsigned int n_mask_elems = (unsigned int)in_sizes[0];   // 33,554,432
    const unsigned int G = n_mask_elems / C_PER_GROUP;             // 8,388,608 groups
    const float inv_n = 1.0f / (float)n_mask_elems;

    // Harness re-poisons d_out to 0xAA before every timed replay: zero it here.
    hipMemsetAsync(d_out, 0, sizeof(float), stream);

    const int block = 256;
    const int grid  = 4096;   // 1,048,576 threads -> 8 groups/thread grid-stride
    recon_loss_kernel<<<grid, block, 0, stream>>>(masks, src, out, G, inv_n);
}